// Round 13
// baseline (485.069 us; speedup 1.0000x reference)
//
#include <hip/hip_runtime.h>

typedef float f32x4 __attribute__((ext_vector_type(4)));
typedef float f32x2 __attribute__((ext_vector_type(2)));
typedef short s16x8 __attribute__((ext_vector_type(8)));

#define N_OUT 66049
#define K_DIM 1024
#define NPANEL 517           // ceil(66049/128)

// round-to-nearest-even f32 -> bf16 (finite inputs)
__device__ __forceinline__ ushort f2bf(float f) {
    union { float f; unsigned u; } x; x.f = f;
    unsigned r = x.u + 0x7fffu + ((x.u >> 16) & 1u);
    return (ushort)(r >> 16);
}

// packed f32x2 -> bf16x2 (RNE)
__device__ __forceinline__ unsigned cvt_pk_bf16(float lo, float hi) {
    unsigned r;
    asm("v_cvt_pk_bf16_f32 %0, %1, %2" : "=v"(r) : "v"(lo), "v"(hi));
    return r;
}

// 16B global -> LDS direct (wave-uniform LDS base + lane*16; global addr per-lane)
__device__ __forceinline__ void lds_load16(const void* g, void* l) {
    auto gp = reinterpret_cast<const __attribute__((address_space(1))) char*>(
        reinterpret_cast<uintptr_t>(g));
    auto lp = reinterpret_cast<__attribute__((address_space(3))) char*>(
        reinterpret_cast<uintptr_t>(l));
    __builtin_amdgcn_global_load_lds(gp, lp, 16, 0, 0);
}

// ---------------- MLP chain body: 4 rows per block, x/h1/h2 in LDS ----------------
__device__ __forceinline__ void chain_body(
    int bid, int tid, char* smem,
    const float* __restrict__ noise, const int* __restrict__ orders,
    const float* __restrict__ emb,
    const float* __restrict__ W1, const float* __restrict__ b1,
    const float* __restrict__ W2, const float* __restrict__ b2,
    const float* __restrict__ W3, const float* __restrict__ b3,
    ushort* __restrict__ h3)
{
    float* xs  = (float*)smem;            // [4][120]
    float* h1s = (float*)(smem + 1920);   // [4][256]
    float* h2s = (float*)(smem + 6016);   // [4][512]
    const int R0 = bid * 4;

    for (int i = tid; i < 4 * 116; i += 256) {
        const int r = i / 116, c = i - r * 116;
        xs[r * 120 + c] = (c < 100) ? noise[(R0 + r) * 100 + c]
                                    : emb[orders[R0 + r] * 16 + (c - 100)];
    }
    __syncthreads();

    // L1: 116 -> 256, thread owns col tid
    {
        const float bb = b1[tid];
        float a0 = bb, a1 = bb, a2 = bb, a3 = bb;
        #pragma unroll 4
        for (int k = 0; k < 116; ++k) {
            const float w = W1[k * 256 + tid];
            a0 = fmaf(xs[0 * 120 + k], w, a0);
            a1 = fmaf(xs[1 * 120 + k], w, a1);
            a2 = fmaf(xs[2 * 120 + k], w, a2);
            a3 = fmaf(xs[3 * 120 + k], w, a3);
        }
        h1s[0 * 256 + tid] = fmaxf(a0, 0.f);
        h1s[1 * 256 + tid] = fmaxf(a1, 0.f);
        h1s[2 * 256 + tid] = fmaxf(a2, 0.f);
        h1s[3 * 256 + tid] = fmaxf(a3, 0.f);
    }
    __syncthreads();

    // L2: 256 -> 512, thread owns cols {2t, 2t+1}
    {
        const f32x2 bb = *reinterpret_cast<const f32x2*>(&b2[tid * 2]);
        f32x2 a[4] = {bb, bb, bb, bb};
        for (int k = 0; k < 256; k += 4) {
            f32x4 hh[4];
            #pragma unroll
            for (int r = 0; r < 4; ++r) hh[r] = *reinterpret_cast<const f32x4*>(&h1s[r * 256 + k]);
            #pragma unroll
            for (int kk = 0; kk < 4; ++kk) {
                const f32x2 w = *reinterpret_cast<const f32x2*>(&W2[(k + kk) * 512 + tid * 2]);
                #pragma unroll
                for (int r = 0; r < 4; ++r) {
                    a[r][0] = fmaf(hh[r][kk], w[0], a[r][0]);
                    a[r][1] = fmaf(hh[r][kk], w[1], a[r][1]);
                }
            }
        }
        #pragma unroll
        for (int r = 0; r < 4; ++r) {
            h2s[r * 512 + tid * 2]     = fmaxf(a[r][0], 0.f);
            h2s[r * 512 + tid * 2 + 1] = fmaxf(a[r][1], 0.f);
        }
    }
    __syncthreads();

    // L3: 512 -> 1024, thread owns cols 4t..4t+3, bf16 output
    {
        const f32x4 bb = *reinterpret_cast<const f32x4*>(&b3[tid * 4]);
        f32x4 a[4] = {bb, bb, bb, bb};
        for (int k = 0; k < 512; k += 4) {
            f32x4 hh[4];
            #pragma unroll
            for (int r = 0; r < 4; ++r) hh[r] = *reinterpret_cast<const f32x4*>(&h2s[r * 512 + k]);
            #pragma unroll
            for (int kk = 0; kk < 4; ++kk) {
                const f32x4 w = *reinterpret_cast<const f32x4*>(&W3[(k + kk) * 1024 + tid * 4]);
                #pragma unroll
                for (int r = 0; r < 4; ++r) {
                    a[r][0] = fmaf(hh[r][kk], w[0], a[r][0]);
                    a[r][1] = fmaf(hh[r][kk], w[1], a[r][1]);
                    a[r][2] = fmaf(hh[r][kk], w[2], a[r][2]);
                    a[r][3] = fmaf(hh[r][kk], w[3], a[r][3]);
                }
            }
        }
        #pragma unroll
        for (int r = 0; r < 4; ++r) {
            ushort4 u;
            u.x = f2bf(fmaxf(a[r][0], 0.f));
            u.y = f2bf(fmaxf(a[r][1], 0.f));
            u.z = f2bf(fmaxf(a[r][2], 0.f));
            u.w = f2bf(fmaxf(a[r][3], 0.f));
            *reinterpret_cast<ushort4*>(&h3[(size_t)(R0 + r) * 1024 + tid * 4]) = u;
        }
    }
}

// ------- convert body: W_out (f32 [K][N]) -> Bp (bf16 [panel128][kb(128)][nl(128)][kj8]) -------
// LDS-transpose of a 64x128 f32 tile. NT loads on Wout (read-once stream) keep Bp L3-resident.
__device__ __forceinline__ void convert_wout_body(
    int p, int kt, int tid, char* smem,
    const float* __restrict__ Wout, ushort* __restrict__ Bp)
{
    float* T = (float*)smem;                      // [64][132] (+4 pad)
    const int k0 = kt * 64;

    if (p < NPANEL - 1) {
        const int c4 = (tid & 31) * 4;
        const int r0 = tid >> 5;
        const float* src = Wout + (size_t)k0 * N_OUT + (size_t)p * 128 + c4;
        #pragma unroll
        for (int i = 0; i < 8; ++i) {
            const int r = r0 + i * 8;
            f32x4 v = __builtin_nontemporal_load(
                reinterpret_cast<const f32x4*>(src + (size_t)r * N_OUT));
            *reinterpret_cast<f32x4*>(&T[r * 132 + c4]) = v;
        }
    } else {
        // last panel (only col 66048 valid): scalar, col-clamped (no OOB reads)
        const int c = tid & 31, r0 = tid >> 5;
        #pragma unroll
        for (int i = 0; i < 8; ++i) {
            const int r = r0 + i * 8;
            #pragma unroll
            for (int j = 0; j < 4; ++j) {
                int col = p * 128 + c * 4 + j;
                if (col > N_OUT - 1) col = N_OUT - 1;
                T[r * 132 + c * 4 + j] = Wout[(size_t)(k0 + r) * N_OUT + col];
            }
        }
    }
    __syncthreads();

    const size_t base = ((size_t)p * 128 + kt * 8) * 128 * 8;   // ushort index
    #pragma unroll
    for (int i = 0; i < 4; ++i) {
        const int v = tid + i * 256;
        const int kbl = v >> 7, nl = v & 127;
        s16x8 o;
        #pragma unroll
        for (int j = 0; j < 8; ++j) o[j] = (short)f2bf(T[(kbl * 8 + j) * 132 + nl]);
        *reinterpret_cast<s16x8*>(Bp + base + (size_t)v * 8) = o;
    }
}

// ---------------- prep: chain blocks [0,256) ∥ convert blocks [256, 256+NPANEL*16) ----------------
__global__ __launch_bounds__(256) void prep(
    const float* __restrict__ noise, const int* __restrict__ orders,
    const float* __restrict__ emb,
    const float* __restrict__ W1, const float* __restrict__ b1,
    const float* __restrict__ W2, const float* __restrict__ b2,
    const float* __restrict__ W3, const float* __restrict__ b3,
    const float* __restrict__ Wout,
    ushort* __restrict__ h3, ushort* __restrict__ Bp)
{
    __shared__ __align__(16) char smem[33792];
    const int bx = blockIdx.x;
    const int tid = threadIdx.x;
    if (bx < 256) {
        chain_body(bx, tid, smem, noise, orders, emb, W1, b1, W2, b2, W3, b3, h3);
    } else {
        const int c = bx - 256;
        const int p  = c % NPANEL;            // panel fast (row-band-major)
        const int kt = c / NPANEL;
        convert_wout_body(p, kt, tid, smem, Wout, Bp);
    }
}

// ---------------- big GEMM: out = sigmoid(h3 @ Bp + bout) ----------------
// ALL-DIRECT main loop: no LDS, no barriers, no global_load_lds. Every MFMA fragment
// is a contiguous 16B in global (h3 row-major k-contig; Bp k-major) and L2-resident
// (h3 = 2 MB; Bp panel = 512 KB shared by 8 XCD-grouped m-blocks). Two-stage software
// pipeline over 32 half-K steps (8 loads + 16 MFMA per stage); waves run barrier-free.
// A frag (fm,s) = h3[(m0+arow+fm*16)*1024 + s*32 + u4*8]  (swizzle algebra inverted)
// B frag (fn,s) = BpPanel[s*4096 + u4*1024 + (bn+fn*16)*8]
__global__ __launch_bounds__(256, 3) void gemm_out(
    const ushort* __restrict__ h3, const ushort* __restrict__ Bp,
    const float* __restrict__ bout, float* __restrict__ out)
{
    __shared__ __align__(16) char smem[33792];   // epilogue staging only

    const int tid = threadIdx.x;
    const int lane = tid & 63;
    const int w = tid >> 6;
    const int wm = w >> 1, wn = w & 1;
    const int u4 = lane >> 4, l15 = lane & 15;

    // XCD-grouped mapping: 8 m-blocks of a panel land on one XCD (B panel L2 reuse)
    const int raw = blockIdx.x;
    const int panel = (raw >> 6) * 8 + (raw & 7);
    const int mblk = (raw >> 3) & 7;
    if (panel >= NPANEL) return;
    const int m0 = mblk * 128;
    const int n0 = panel * 128;

    f32x4 acc[4][4] = {};

    const int arow = wm * 64 + l15;          // + fm*16
    const int bn   = wn * 64 + l15;          // + fn*16

    const ushort* ap0 = h3 + ((size_t)(m0 + arow) << 10) + u4 * 8;
    const ushort* ap1 = ap0 + (16 << 10);
    const ushort* ap2 = ap0 + (32 << 10);
    const ushort* ap3 = ap0 + (48 << 10);
    const ushort* bp  = Bp + (size_t)panel * (128 * 128 * 8) + u4 * 1024 + bn * 8;

    s16x8 a0[4], b0[4], a1[4], b1[4];

    auto LD = [&](int s, s16x8* A, s16x8* B) {
        const int ao = s * 32;
        A[0] = *reinterpret_cast<const s16x8*>(ap0 + ao);
        A[1] = *reinterpret_cast<const s16x8*>(ap1 + ao);
        A[2] = *reinterpret_cast<const s16x8*>(ap2 + ao);
        A[3] = *reinterpret_cast<const s16x8*>(ap3 + ao);
        const ushort* bs = bp + (size_t)s * 4096;
        #pragma unroll
        for (int fn = 0; fn < 4; ++fn)
            B[fn] = *reinterpret_cast<const s16x8*>(bs + fn * 128);
    };
    auto MM = [&](s16x8* A, s16x8* B) {
        #pragma unroll
        for (int fm = 0; fm < 4; ++fm)
            #pragma unroll
            for (int fn = 0; fn < 4; ++fn)
                acc[fm][fn] = __builtin_amdgcn_mfma_f32_16x16x32_bf16(
                    A[fm], B[fn], acc[fm][fn], 0, 0, 0);
    };

    // two-stage pipeline: loads for stage s+1 issue before MFMA of stage s completes
    LD(0, a0, b0);
    for (int s = 0; s < 32; s += 2) {
        if (s + 1 < 32) LD(s + 1, a1, b1);
        MM(a0, b0);
        if (s + 2 < 32) LD(s + 2, a0, b0);
        if (s + 1 < 32) MM(a1, b1);
    }

    // ---- epilogue: sigmoid -> LDS [64][132] f32 -> 512 B row-segment NT stores ----
    if (n0 + 128 <= N_OUT) {
        float bo[4];
        #pragma unroll
        for (int fn = 0; fn < 4; ++fn) bo[fn] = bout[n0 + wn * 64 + fn * 16 + l15];
        float* Elds = (float*)smem;
        #pragma unroll
        for (int p = 0; p < 2; ++p) {
            if (wm == p) {
                #pragma unroll
                for (int fm = 0; fm < 4; ++fm)
                    #pragma unroll
                    for (int fn = 0; fn < 4; ++fn)
                        #pragma unroll
                        for (int j = 0; j < 4; ++j) {
                            const int rl = fm * 16 + u4 * 4 + j;       // 0..63
                            const int cl = wn * 64 + fn * 16 + l15;    // 0..127
                            const float z = acc[fm][fn][j] + bo[fn];
                            Elds[rl * 132 + cl] = 1.f / (1.f + __expf(-z));
                        }
            }
            __syncthreads();
            const size_t gb = (size_t)(m0 + p * 64) * N_OUT + n0;
            const int g = tid >> 5, c4 = (tid & 31) * 4;
            #pragma unroll
            for (int i = 0; i < 8; ++i) {
                const int rl = i * 8 + g;                              // 0..63
                const f32x4 v = *reinterpret_cast<const f32x4*>(&Elds[rl * 132 + c4]);
                __builtin_nontemporal_store(v,
                    reinterpret_cast<f32x4*>(&out[gb + (size_t)rl * N_OUT + c4]));
            }
            __syncthreads();
        }
    } else {
        // last panel: scalar guarded stores
        const int rbase = m0 + wm * 64 + u4 * 4;
        #pragma unroll
        for (int fn = 0; fn < 4; ++fn) {
            const int col = n0 + wn * 64 + fn * 16 + l15;
            const bool ok = col < N_OUT;
            const float bo = bout[ok ? col : (N_OUT - 1)];
            #pragma unroll
            for (int fm = 0; fm < 4; ++fm) {
                #pragma unroll
                for (int j = 0; j < 4; ++j) {
                    if (ok) {
                        const int row = rbase + fm * 16 + j;
                        const float z = acc[fm][fn][j] + bo;
                        out[(size_t)row * N_OUT + col] = 1.f / (1.f + __expf(-z));
                    }
                }
            }
        }
    }
}

// ---------------- fallback (ws too small for Bp): fused in-loop convert, 128x128 ----------------
__global__ __launch_bounds__(256) void gemm_out_fused(
    const ushort* __restrict__ h3, const float* __restrict__ Wout,
    const float* __restrict__ bout, float* __restrict__ out)
{
    __shared__ __align__(16) char smem[33792];
    ushort* Alds = (ushort*)smem;
    ushort* Blds = (ushort*)(smem + 16384);

    const int tid = threadIdx.x;
    const int lane = tid & 63;
    const int w = tid >> 6;
    const int wm = w >> 1, wn = w & 1;

    const int raw = blockIdx.x;
    const int panel = (raw >> 6) * 8 + (raw & 7);
    const int mblk = (raw >> 3) & 7;
    if (panel >= NPANEL) return;
    const int m0 = mblk * 128;
    const int n0 = panel * 128;

    const int nl = tid & 127;
    const int kb0 = tid >> 7;
    int nc = n0 + nl; if (nc > N_OUT - 1) nc = N_OUT - 1;
    const float* Bsrc = Wout + nc;

    f32x4 acc[4][4] = {};
    float breg[32];

    const int arow = wm * 64 + (lane & 15);
    const int ac0  = lane >> 4;
    const int bn   = wn * 64 + (lane & 15);

    auto stageA = [&](int kt) {
        const int k0 = kt * 64;
        #pragma unroll
        for (int i = 0; i < 4; ++i) {
            const int u = (w * 4 + i) * 64 + lane;
            const int r = u >> 3, cc = u & 7;
            const ushort* src = h3 + (size_t)(m0 + r) * K_DIM + (k0 + ((cc ^ (r & 7)) << 3));
            lds_load16(src, (void*)&Alds[(w * 4 + i) * 512]);
        }
    };
    auto loadB = [&](int kt) {
        const int k0 = kt * 64;
        #pragma unroll
        for (int g = 0; g < 4; ++g) {
            const int kb = kb0 + g * 2;
            #pragma unroll
            for (int i = 0; i < 8; ++i)
                breg[g * 8 + i] = Bsrc[(size_t)(k0 + kb * 8 + i) * N_OUT];
        }
    };
    auto writeB = [&]() {
        #pragma unroll
        for (int g = 0; g < 4; ++g) {
            const int kb = kb0 + g * 2;
            union { s16x8 v; unsigned u[4]; } pk;
            #pragma unroll
            for (int h = 0; h < 4; ++h)
                pk.u[h] = cvt_pk_bf16(breg[g * 8 + 2 * h], breg[g * 8 + 2 * h + 1]);
            *reinterpret_cast<s16x8*>(&Blds[(kb * 128 + nl) * 8]) = pk.v;
        }
    };
    auto compute = [&]() {
        #pragma unroll
        for (int ks = 0; ks < 2; ++ks) {
            s16x8 af[4], bfr[4];
            #pragma unroll
            for (int fm = 0; fm < 4; ++fm) {
                const int r = arow + fm * 16;
                const int cc = (ks * 4 + ac0) ^ (r & 7);
                af[fm] = *reinterpret_cast<const s16x8*>(&Alds[r * 64 + cc * 8]);
            }
            const int kb = ks * 4 + ac0;
            #pragma unroll
            for (int fn = 0; fn < 4; ++fn)
                bfr[fn] = *reinterpret_cast<const s16x8*>(&Blds[(kb * 128 + bn + fn * 16) * 8]);
            #pragma unroll
            for (int fm = 0; fm < 4; ++fm)
                #pragma unroll
                for (int fn = 0; fn < 4; ++fn)
                    acc[fm][fn] = __builtin_amdgcn_mfma_f32_16x16x32_bf16(
                        af[fm], bfr[fn], acc[fm][fn], 0, 0, 0);
        }
    };

    stageA(0);
    loadB(0);
    asm volatile("s_waitcnt vmcnt(0)" ::: "memory");
    asm volatile("s_barrier" ::: "memory");
    writeB();
    loadB(1);
    asm volatile("s_waitcnt lgkmcnt(0)" ::: "memory");
    asm volatile("s_barrier" ::: "memory");

    for (int kt = 0; kt < 16; ++kt) {
        compute();
        asm volatile("s_barrier" ::: "memory");
        if (kt < 15) {
            stageA(kt + 1);
            __builtin_amdgcn_sched_barrier(0);
            writeB();
            if (kt < 14) {
                loadB(kt + 2);
                asm volatile("s_waitcnt lgkmcnt(0)" ::: "memory");
                asm volatile("s_waitcnt vmcnt(32)" ::: "memory");
            } else {
                asm volatile("s_waitcnt lgkmcnt(0)" ::: "memory");
                asm volatile("s_waitcnt vmcnt(0)" ::: "memory");
            }
            asm volatile("s_barrier" ::: "memory");
        }
    }

    if (n0 + 128 <= N_OUT) {
        float bo[4];
        #pragma unroll
        for (int fn = 0; fn < 4; ++fn) bo[fn] = bout[n0 + wn * 64 + fn * 16 + (lane & 15)];
        float* Elds = (float*)smem;
        #pragma unroll
        for (int p = 0; p < 2; ++p) {
            if (wm == p) {
                #pragma unroll
                for (int fm = 0; fm < 4; ++fm)
                    #pragma unroll
                    for (int fn = 0; fn < 4; ++fn)
                        #pragma unroll
                        for (int j = 0; j < 4; ++j) {
                            const int rl = fm * 16 + (lane >> 4) * 4 + j;
                            const int cl = wn * 64 + fn * 16 + (lane & 15);
                            const float z = acc[fm][fn][j] + bo[fn];
                            Elds[rl * 132 + cl] = 1.f / (1.f + __expf(-z));
                        }
            }
            __syncthreads();
            const size_t gb = (size_t)(m0 + p * 64) * N_OUT + n0;
            const int g = tid >> 5, c4 = (tid & 31) * 4;
            #pragma unroll
            for (int i = 0; i < 8; ++i) {
                const int rl = i * 8 + g;
                const f32x4 v = *reinterpret_cast<const f32x4*>(&Elds[rl * 132 + c4]);
                *reinterpret_cast<f32x4*>(&out[gb + (size_t)rl * N_OUT + c4]) = v;
            }
            __syncthreads();
        }
    } else {
        const int rbase = m0 + wm * 64 + (lane >> 4) * 4;
        #pragma unroll
        for (int fn = 0; fn < 4; ++fn) {
            const int col = n0 + wn * 64 + fn * 16 + (lane & 15);
            const bool ok = col < N_OUT;
            const float bo = bout[ok ? col : (N_OUT - 1)];
            #pragma unroll
            for (int fm = 0; fm < 4; ++fm) {
                #pragma unroll
                for (int j = 0; j < 4; ++j) {
                    if (ok) {
                        const int row = rbase + fm * 16 + j;
                        const float z = acc[fm][fn][j] + bo;
                        out[(size_t)row * N_OUT + col] = 1.f / (1.f + __expf(-z));
                    }
                }
            }
        }
    }
}

extern "C" void kernel_launch(void* const* d_in, const int* in_sizes, int n_in,
                              void* d_out, int out_size, void* d_ws, size_t ws_size,
                              hipStream_t stream)
{
    const float* noise = (const float*)d_in[0];
    const int*   orders = (const int*)d_in[1];
    const float* emb   = (const float*)d_in[2];
    const float* W1 = (const float*)d_in[3];
    const float* b1 = (const float*)d_in[4];
    const float* W2 = (const float*)d_in[5];
    const float* b2 = (const float*)d_in[6];
    const float* W3 = (const float*)d_in[7];
    const float* b3 = (const float*)d_in[8];
    const float* Wout = (const float*)d_in[9];
    const float* bout = (const float*)d_in[10];

    char* ws = (char*)d_ws;
    ushort* h3 = (ushort*)ws;                 // 2 MB bf16
    ushort* Bp = (ushort*)(ws + 0x200000);    // 517*128*128*8*2 = 135.5 MB
    const size_t need = 0x200000 + (size_t)NPANEL * 128 * 128 * 8 * 2;
    const bool pre = (ws_size >= need);

    if (pre) {
        prep<<<256 + NPANEL * 16, 256, 0, stream>>>(
            noise, orders, emb, W1, b1, W2, b2, W3, b3, Wout, h3, Bp);
        gemm_out<<<4160, 256, 0, stream>>>(h3, Bp, bout, (float*)d_out);
    } else {
        prep<<<256, 256, 0, stream>>>(
            noise, orders, emb, W1, b1, W2, b2, W3, b3, Wout, h3, Bp);
        gemm_out_fused<<<4160, 256, 0, stream>>>(h3, Wout, bout, (float*)d_out);
    }
}

// Round 14
// 305.259 us; speedup vs baseline: 1.5890x; 1.5890x over previous
//
#include <hip/hip_runtime.h>

typedef float f32x4 __attribute__((ext_vector_type(4)));
typedef float f32x2 __attribute__((ext_vector_type(2)));
typedef short s16x8 __attribute__((ext_vector_type(8)));

#define N_OUT 66049
#define K_DIM 1024
#define NPANEL 517           // ceil(66049/128)

// round-to-nearest-even f32 -> bf16 (finite inputs)
__device__ __forceinline__ ushort f2bf(float f) {
    union { float f; unsigned u; } x; x.f = f;
    unsigned r = x.u + 0x7fffu + ((x.u >> 16) & 1u);
    return (ushort)(r >> 16);
}

// packed f32x2 -> bf16x2 (RNE)
__device__ __forceinline__ unsigned cvt_pk_bf16(float lo, float hi) {
    unsigned r;
    asm("v_cvt_pk_bf16_f32 %0, %1, %2" : "=v"(r) : "v"(lo), "v"(hi));
    return r;
}

// 16B global -> LDS direct (wave-uniform LDS base + lane*16; global addr per-lane)
__device__ __forceinline__ void lds_load16(const void* g, void* l) {
    auto gp = reinterpret_cast<const __attribute__((address_space(1))) char*>(
        reinterpret_cast<uintptr_t>(g));
    auto lp = reinterpret_cast<__attribute__((address_space(3))) char*>(
        reinterpret_cast<uintptr_t>(l));
    __builtin_amdgcn_global_load_lds(gp, lp, 16, 0, 0);
}

// ---------------- MLP chain body: 4 rows per block, x/h1/h2 in LDS ----------------
__device__ __forceinline__ void chain_body(
    int bid, int tid, char* smem,
    const float* __restrict__ noise, const int* __restrict__ orders,
    const float* __restrict__ emb,
    const float* __restrict__ W1, const float* __restrict__ b1,
    const float* __restrict__ W2, const float* __restrict__ b2,
    const float* __restrict__ W3, const float* __restrict__ b3,
    ushort* __restrict__ h3)
{
    float* xs  = (float*)smem;            // [4][120]
    float* h1s = (float*)(smem + 1920);   // [4][256]
    float* h2s = (float*)(smem + 6016);   // [4][512]
    const int R0 = bid * 4;

    for (int i = tid; i < 4 * 116; i += 256) {
        const int r = i / 116, c = i - r * 116;
        xs[r * 120 + c] = (c < 100) ? noise[(R0 + r) * 100 + c]
                                    : emb[orders[R0 + r] * 16 + (c - 100)];
    }
    __syncthreads();

    // L1: 116 -> 256, thread owns col tid
    {
        const float bb = b1[tid];
        float a0 = bb, a1 = bb, a2 = bb, a3 = bb;
        #pragma unroll 4
        for (int k = 0; k < 116; ++k) {
            const float w = W1[k * 256 + tid];
            a0 = fmaf(xs[0 * 120 + k], w, a0);
            a1 = fmaf(xs[1 * 120 + k], w, a1);
            a2 = fmaf(xs[2 * 120 + k], w, a2);
            a3 = fmaf(xs[3 * 120 + k], w, a3);
        }
        h1s[0 * 256 + tid] = fmaxf(a0, 0.f);
        h1s[1 * 256 + tid] = fmaxf(a1, 0.f);
        h1s[2 * 256 + tid] = fmaxf(a2, 0.f);
        h1s[3 * 256 + tid] = fmaxf(a3, 0.f);
    }
    __syncthreads();

    // L2: 256 -> 512, thread owns cols {2t, 2t+1}
    {
        const f32x2 bb = *reinterpret_cast<const f32x2*>(&b2[tid * 2]);
        f32x2 a[4] = {bb, bb, bb, bb};
        for (int k = 0; k < 256; k += 4) {
            f32x4 hh[4];
            #pragma unroll
            for (int r = 0; r < 4; ++r) hh[r] = *reinterpret_cast<const f32x4*>(&h1s[r * 256 + k]);
            #pragma unroll
            for (int kk = 0; kk < 4; ++kk) {
                const f32x2 w = *reinterpret_cast<const f32x2*>(&W2[(k + kk) * 512 + tid * 2]);
                #pragma unroll
                for (int r = 0; r < 4; ++r) {
                    a[r][0] = fmaf(hh[r][kk], w[0], a[r][0]);
                    a[r][1] = fmaf(hh[r][kk], w[1], a[r][1]);
                }
            }
        }
        #pragma unroll
        for (int r = 0; r < 4; ++r) {
            h2s[r * 512 + tid * 2]     = fmaxf(a[r][0], 0.f);
            h2s[r * 512 + tid * 2 + 1] = fmaxf(a[r][1], 0.f);
        }
    }
    __syncthreads();

    // L3: 512 -> 1024, thread owns cols 4t..4t+3, bf16 output
    {
        const f32x4 bb = *reinterpret_cast<const f32x4*>(&b3[tid * 4]);
        f32x4 a[4] = {bb, bb, bb, bb};
        for (int k = 0; k < 512; k += 4) {
            f32x4 hh[4];
            #pragma unroll
            for (int r = 0; r < 4; ++r) hh[r] = *reinterpret_cast<const f32x4*>(&h2s[r * 512 + k]);
            #pragma unroll
            for (int kk = 0; kk < 4; ++kk) {
                const f32x4 w = *reinterpret_cast<const f32x4*>(&W3[(k + kk) * 1024 + tid * 4]);
                #pragma unroll
                for (int r = 0; r < 4; ++r) {
                    a[r][0] = fmaf(hh[r][kk], w[0], a[r][0]);
                    a[r][1] = fmaf(hh[r][kk], w[1], a[r][1]);
                    a[r][2] = fmaf(hh[r][kk], w[2], a[r][2]);
                    a[r][3] = fmaf(hh[r][kk], w[3], a[r][3]);
                }
            }
        }
        #pragma unroll
        for (int r = 0; r < 4; ++r) {
            ushort4 u;
            u.x = f2bf(fmaxf(a[r][0], 0.f));
            u.y = f2bf(fmaxf(a[r][1], 0.f));
            u.z = f2bf(fmaxf(a[r][2], 0.f));
            u.w = f2bf(fmaxf(a[r][3], 0.f));
            *reinterpret_cast<ushort4*>(&h3[(size_t)(R0 + r) * 1024 + tid * 4]) = u;
        }
    }
}

// ------- convert body: W_out (f32 [K][N]) -> Bp (bf16 [panel128][kb(128)][nl(128)][kj8]) -------
// LDS-transpose of a 64x128 f32 tile. NT loads on Wout (read-once stream) keep Bp L3-resident.
__device__ __forceinline__ void convert_wout_body(
    int p, int kt, int tid, char* smem,
    const float* __restrict__ Wout, ushort* __restrict__ Bp)
{
    float* T = (float*)smem;                      // [64][132] (+4 pad)
    const int k0 = kt * 64;

    if (p < NPANEL - 1) {
        const int c4 = (tid & 31) * 4;
        const int r0 = tid >> 5;
        const float* src = Wout + (size_t)k0 * N_OUT + (size_t)p * 128 + c4;
        #pragma unroll
        for (int i = 0; i < 8; ++i) {
            const int r = r0 + i * 8;
            f32x4 v = __builtin_nontemporal_load(
                reinterpret_cast<const f32x4*>(src + (size_t)r * N_OUT));
            *reinterpret_cast<f32x4*>(&T[r * 132 + c4]) = v;
        }
    } else {
        // last panel (only col 66048 valid): scalar, col-clamped (no OOB reads)
        const int c = tid & 31, r0 = tid >> 5;
        #pragma unroll
        for (int i = 0; i < 8; ++i) {
            const int r = r0 + i * 8;
            #pragma unroll
            for (int j = 0; j < 4; ++j) {
                int col = p * 128 + c * 4 + j;
                if (col > N_OUT - 1) col = N_OUT - 1;
                T[r * 132 + c * 4 + j] = Wout[(size_t)(k0 + r) * N_OUT + col];
            }
        }
    }
    __syncthreads();

    const size_t base = ((size_t)p * 128 + kt * 8) * 128 * 8;   // ushort index
    #pragma unroll
    for (int i = 0; i < 4; ++i) {
        const int v = tid + i * 256;
        const int kbl = v >> 7, nl = v & 127;
        s16x8 o;
        #pragma unroll
        for (int j = 0; j < 8; ++j) o[j] = (short)f2bf(T[(kbl * 8 + j) * 132 + nl]);
        *reinterpret_cast<s16x8*>(Bp + base + (size_t)v * 8) = o;
    }
}

// ---------------- prep: chain blocks [0,256) ∥ convert blocks [256, 256+NPANEL*16) ----------------
__global__ __launch_bounds__(256) void prep(
    const float* __restrict__ noise, const int* __restrict__ orders,
    const float* __restrict__ emb,
    const float* __restrict__ W1, const float* __restrict__ b1,
    const float* __restrict__ W2, const float* __restrict__ b2,
    const float* __restrict__ W3, const float* __restrict__ b3,
    const float* __restrict__ Wout,
    ushort* __restrict__ h3, ushort* __restrict__ Bp)
{
    __shared__ __align__(16) char smem[33792];
    const int bx = blockIdx.x;
    const int tid = threadIdx.x;
    if (bx < 256) {
        chain_body(bx, tid, smem, noise, orders, emb, W1, b1, W2, b2, W3, b3, h3);
    } else {
        const int c = bx - 256;
        const int p  = c % NPANEL;            // panel fast (row-band-major)
        const int kt = c / NPANEL;
        convert_wout_body(p, kt, tid, smem, Wout, Bp);
    }
}

// ---------------- big GEMM: out = sigmoid(h3 @ Bp + bout) ----------------
// m97 structure: 128x128 tile, BK=64, 4 waves (2x2), single-buffer LDS, 2 barriers/K-step.
// LDS-staged aligned epilogue with NT stores (out never re-read) -> Bp/h3 stay L3-resident.
__global__ __launch_bounds__(256, 4) void gemm_out(
    const ushort* __restrict__ h3, const ushort* __restrict__ Bp,
    const float* __restrict__ bout, float* __restrict__ out)
{
    __shared__ __align__(16) char smem[33792];
    ushort* Alds = (ushort*)smem;             // [128 r][8 units], XOR-swizzled source
    ushort* Blds = (ushort*)(smem + 16384);   // [kbl(8)][nl(128)][kj(8)]

    const int tid = threadIdx.x;
    const int lane = tid & 63;
    const int w = tid >> 6;
    const int wm = w >> 1, wn = w & 1;

    // XCD-grouped mapping: 8 m-blocks of a panel land on one XCD (B panel L2 reuse)
    const int raw = blockIdx.x;
    const int panel = (raw >> 6) * 8 + (raw & 7);
    const int mblk = (raw >> 3) & 7;
    if (panel >= NPANEL) return;
    const int m0 = mblk * 128;
    const int n0 = panel * 128;

    f32x4 acc[4][4] = {};

    const int arow = wm * 64 + (lane & 15);  // + fm*16
    const int ac0  = lane >> 4;
    const int bn   = wn * 64 + (lane & 15);  // + fn*16

    const ushort* BpPanel = Bp + (size_t)panel * (128 * 128 * 8);

    for (int kt = 0; kt < 16; ++kt) {
        const int k0 = kt * 64;
        // ---- stage A (16 KB) : 4 global_load_lds per thread, swizzled source ----
        #pragma unroll
        for (int i = 0; i < 4; ++i) {
            const int u = (w * 4 + i) * 64 + lane;       // linear 16B unit
            const int r = u >> 3, cc = u & 7;
            const ushort* src = h3 + (size_t)(m0 + r) * K_DIM + (k0 + ((cc ^ (r & 7)) << 3));
            lds_load16(src, (void*)&Alds[(w * 4 + i) * 512]);
        }
        // ---- stage B (16 KB) : contiguous chunk, linear copy ----
        const ushort* bsrc = BpPanel + (size_t)kt * 8192;
        #pragma unroll
        for (int i = 0; i < 4; ++i) {
            const int u = (w * 4 + i) * 64 + lane;
            lds_load16(bsrc + (size_t)u * 8, (void*)&Blds[(w * 4 + i) * 512]);
        }
        __syncthreads();   // compiler drains vmcnt(0) here

        // ---- compute: 16 ds_read_b128 + 32 MFMA per thread ----
        #pragma unroll
        for (int ks = 0; ks < 2; ++ks) {
            s16x8 af[4], bfr[4];
            #pragma unroll
            for (int fm = 0; fm < 4; ++fm) {
                const int r = arow + fm * 16;
                const int cc = (ks * 4 + ac0) ^ (r & 7);
                af[fm] = *reinterpret_cast<const s16x8*>(&Alds[r * 64 + cc * 8]);
            }
            const int kbl = ks * 4 + ac0;
            #pragma unroll
            for (int fn = 0; fn < 4; ++fn)
                bfr[fn] = *reinterpret_cast<const s16x8*>(&Blds[(kbl * 128 + bn + fn * 16) * 8]);
            #pragma unroll
            for (int fm = 0; fm < 4; ++fm)
                #pragma unroll
                for (int fn = 0; fn < 4; ++fn)
                    acc[fm][fn] = __builtin_amdgcn_mfma_f32_16x16x32_bf16(
                        af[fm], bfr[fn], acc[fm][fn], 0, 0, 0);
        }
        __syncthreads();
    }

    // ---- epilogue: sigmoid -> LDS [64][132] f32 -> 512 B row-segment NT stores ----
    if (n0 + 128 <= N_OUT) {
        float bo[4];
        #pragma unroll
        for (int fn = 0; fn < 4; ++fn) bo[fn] = bout[n0 + wn * 64 + fn * 16 + (lane & 15)];
        float* Elds = (float*)smem;
        #pragma unroll
        for (int p = 0; p < 2; ++p) {
            if (wm == p) {
                #pragma unroll
                for (int fm = 0; fm < 4; ++fm)
                    #pragma unroll
                    for (int fn = 0; fn < 4; ++fn)
                        #pragma unroll
                        for (int j = 0; j < 4; ++j) {
                            const int rl = fm * 16 + (lane >> 4) * 4 + j;      // 0..63
                            const int cl = wn * 64 + fn * 16 + (lane & 15);    // 0..127
                            const float z = acc[fm][fn][j] + bo[fn];
                            Elds[rl * 132 + cl] = 1.f / (1.f + __expf(-z));
                        }
            }
            __syncthreads();
            const size_t gb = (size_t)(m0 + p * 64) * N_OUT + n0;
            const int g = tid >> 5, c4 = (tid & 31) * 4;
            #pragma unroll
            for (int i = 0; i < 8; ++i) {
                const int rl = i * 8 + g;                                      // 0..63
                const f32x4 v = *reinterpret_cast<const f32x4*>(&Elds[rl * 132 + c4]);
                __builtin_nontemporal_store(v,
                    reinterpret_cast<f32x4*>(&out[gb + (size_t)rl * N_OUT + c4]));
            }
            __syncthreads();
        }
    } else {
        // last panel: scalar guarded stores
        const int rbase = m0 + wm * 64 + (lane >> 4) * 4;
        #pragma unroll
        for (int fn = 0; fn < 4; ++fn) {
            const int col = n0 + wn * 64 + fn * 16 + (lane & 15);
            const bool ok = col < N_OUT;
            const float bo = bout[ok ? col : (N_OUT - 1)];
            #pragma unroll
            for (int fm = 0; fm < 4; ++fm) {
                #pragma unroll
                for (int j = 0; j < 4; ++j) {
                    if (ok) {
                        const int row = rbase + fm * 16 + j;
                        const float z = acc[fm][fn][j] + bo;
                        out[(size_t)row * N_OUT + col] = 1.f / (1.f + __expf(-z));
                    }
                }
            }
        }
    }
}

// ---------------- fallback (ws too small for Bp): fused in-loop convert, 128x128 ----------------
__global__ __launch_bounds__(256) void gemm_out_fused(
    const ushort* __restrict__ h3, const float* __restrict__ Wout,
    const float* __restrict__ bout, float* __restrict__ out)
{
    __shared__ __align__(16) char smem[33792];
    ushort* Alds = (ushort*)smem;
    ushort* Blds = (ushort*)(smem + 16384);

    const int tid = threadIdx.x;
    const int lane = tid & 63;
    const int w = tid >> 6;
    const int wm = w >> 1, wn = w & 1;

    const int raw = blockIdx.x;
    const int panel = (raw >> 6) * 8 + (raw & 7);
    const int mblk = (raw >> 3) & 7;
    if (panel >= NPANEL) return;
    const int m0 = mblk * 128;
    const int n0 = panel * 128;

    const int nl = tid & 127;
    const int kb0 = tid >> 7;
    int nc = n0 + nl; if (nc > N_OUT - 1) nc = N_OUT - 1;
    const float* Bsrc = Wout + nc;

    f32x4 acc[4][4] = {};
    float breg[32];

    const int arow = wm * 64 + (lane & 15);
    const int ac0  = lane >> 4;
    const int bn   = wn * 64 + (lane & 15);

    auto stageA = [&](int kt) {
        const int k0 = kt * 64;
        #pragma unroll
        for (int i = 0; i < 4; ++i) {
            const int u = (w * 4 + i) * 64 + lane;
            const int r = u >> 3, cc = u & 7;
            const ushort* src = h3 + (size_t)(m0 + r) * K_DIM + (k0 + ((cc ^ (r & 7)) << 3));
            lds_load16(src, (void*)&Alds[(w * 4 + i) * 512]);
        }
    };
    auto loadB = [&](int kt) {
        const int k0 = kt * 64;
        #pragma unroll
        for (int g = 0; g < 4; ++g) {
            const int kb = kb0 + g * 2;
            #pragma unroll
            for (int i = 0; i < 8; ++i)
                breg[g * 8 + i] = Bsrc[(size_t)(k0 + kb * 8 + i) * N_OUT];
        }
    };
    auto writeB = [&]() {
        #pragma unroll
        for (int g = 0; g < 4; ++g) {
            const int kb = kb0 + g * 2;
            union { s16x8 v; unsigned u[4]; } pk;
            #pragma unroll
            for (int h = 0; h < 4; ++h)
                pk.u[h] = cvt_pk_bf16(breg[g * 8 + 2 * h], breg[g * 8 + 2 * h + 1]);
            *reinterpret_cast<s16x8*>(&Blds[(kb * 128 + nl) * 8]) = pk.v;
        }
    };
    auto compute = [&]() {
        #pragma unroll
        for (int ks = 0; ks < 2; ++ks) {
            s16x8 af[4], bfr[4];
            #pragma unroll
            for (int fm = 0; fm < 4; ++fm) {
                const int r = arow + fm * 16;
                const int cc = (ks * 4 + ac0) ^ (r & 7);
                af[fm] = *reinterpret_cast<const s16x8*>(&Alds[r * 64 + cc * 8]);
            }
            const int kb = ks * 4 + ac0;
            #pragma unroll
            for (int fn = 0; fn < 4; ++fn)
                bfr[fn] = *reinterpret_cast<const s16x8*>(&Blds[(kb * 128 + bn + fn * 16) * 8]);
            #pragma unroll
            for (int fm = 0; fm < 4; ++fm)
                #pragma unroll
                for (int fn = 0; fn < 4; ++fn)
                    acc[fm][fn] = __builtin_amdgcn_mfma_f32_16x16x32_bf16(
                        af[fm], bfr[fn], acc[fm][fn], 0, 0, 0);
        }
    };

    stageA(0);
    loadB(0);
    asm volatile("s_waitcnt vmcnt(0)" ::: "memory");
    asm volatile("s_barrier" ::: "memory");
    writeB();
    loadB(1);
    asm volatile("s_waitcnt lgkmcnt(0)" ::: "memory");
    asm volatile("s_barrier" ::: "memory");

    for (int kt = 0; kt < 16; ++kt) {
        compute();
        asm volatile("s_barrier" ::: "memory");
        if (kt < 15) {
            stageA(kt + 1);
            __builtin_amdgcn_sched_barrier(0);
            writeB();
            if (kt < 14) {
                loadB(kt + 2);
                asm volatile("s_waitcnt lgkmcnt(0)" ::: "memory");
                asm volatile("s_waitcnt vmcnt(32)" ::: "memory");
            } else {
                asm volatile("s_waitcnt lgkmcnt(0)" ::: "memory");
                asm volatile("s_waitcnt vmcnt(0)" ::: "memory");
            }
            asm volatile("s_barrier" ::: "memory");
        }
    }

    if (n0 + 128 <= N_OUT) {
        float bo[4];
        #pragma unroll
        for (int fn = 0; fn < 4; ++fn) bo[fn] = bout[n0 + wn * 64 + fn * 16 + (lane & 15)];
        float* Elds = (float*)smem;
        #pragma unroll
        for (int p = 0; p < 2; ++p) {
            if (wm == p) {
                #pragma unroll
                for (int fm = 0; fm < 4; ++fm)
                    #pragma unroll
                    for (int fn = 0; fn < 4; ++fn)
                        #pragma unroll
                        for (int j = 0; j < 4; ++j) {
                            const int rl = fm * 16 + (lane >> 4) * 4 + j;
                            const int cl = wn * 64 + fn * 16 + (lane & 15);
                            const float z = acc[fm][fn][j] + bo[fn];
                            Elds[rl * 132 + cl] = 1.f / (1.f + __expf(-z));
                        }
            }
            __syncthreads();
            const size_t gb = (size_t)(m0 + p * 64) * N_OUT + n0;
            const int g = tid >> 5, c4 = (tid & 31) * 4;
            #pragma unroll
            for (int i = 0; i < 8; ++i) {
                const int rl = i * 8 + g;
                const f32x4 v = *reinterpret_cast<const f32x4*>(&Elds[rl * 132 + c4]);
                *reinterpret_cast<f32x4*>(&out[gb + (size_t)rl * N_OUT + c4]) = v;
            }
            __syncthreads();
        }
    } else {
        const int rbase = m0 + wm * 64 + (lane >> 4) * 4;
        #pragma unroll
        for (int fn = 0; fn < 4; ++fn) {
            const int col = n0 + wn * 64 + fn * 16 + (lane & 15);
            const bool ok = col < N_OUT;
            const float bo = bout[ok ? col : (N_OUT - 1)];
            #pragma unroll
            for (int fm = 0; fm < 4; ++fm) {
                #pragma unroll
                for (int j = 0; j < 4; ++j) {
                    if (ok) {
                        const int row = rbase + fm * 16 + j;
                        const float z = acc[fm][fn][j] + bo;
                        out[(size_t)row * N_OUT + col] = 1.f / (1.f + __expf(-z));
                    }
                }
            }
        }
    }
}

extern "C" void kernel_launch(void* const* d_in, const int* in_sizes, int n_in,
                              void* d_out, int out_size, void* d_ws, size_t ws_size,
                              hipStream_t stream)
{
    const float* noise = (const float*)d_in[0];
    const int*   orders = (const int*)d_in[1];
    const float* emb   = (const float*)d_in[2];
    const float* W1 = (const float*)d_in[3];
    const float* b1 = (const float*)d_in[4];
    const float* W2 = (const float*)d_in[5];
    const float* b2 = (const float*)d_in[6];
    const float* W3 = (const float*)d_in[7];
    const float* b3 = (const float*)d_in[8];
    const float* Wout = (const float*)d_in[9];
    const float* bout = (const float*)d_in[10];

    char* ws = (char*)d_ws;
    ushort* h3 = (ushort*)ws;                 // 2 MB bf16
    ushort* Bp = (ushort*)(ws + 0x200000);    // 517*128*128*8*2 = 135.5 MB
    const size_t need = 0x200000 + (size_t)NPANEL * 128 * 128 * 8 * 2;
    const bool pre = (ws_size >= need);

    if (pre) {
        prep<<<256 + NPANEL * 16, 256, 0, stream>>>(
            noise, orders, emb, W1, b1, W2, b2, W3, b3, Wout, h3, Bp);
        gemm_out<<<4160, 256, 0, stream>>>(h3, Bp, bout, (float*)d_out);
    } else {
        prep<<<256, 256, 0, stream>>>(
            noise, orders, emb, W1, b1, W2, b2, W3, b3, Wout, h3, Bp);
        gemm_out_fused<<<4160, 256, 0, stream>>>(h3, Wout, bout, (float*)d_out);
    }
}